// Round 4
// baseline (103.054 us; speedup 1.0000x reference)
//
#include <hip/hip_runtime.h>
#include <math.h>

// Problem constants (match reference)
#define BB   16
#define CC   64
#define LL   512
#define LP   16
#define DM   1024
#define NP   64
#define PRD  256   // period = L/2
#define HEAD 128   // PRD/2
#define NV   256   // L - PRD

typedef float f32x4 __attribute__((ext_vector_type(4)));

// ---------------------------------------------------------------------------
// Kernel A: per-(b,l) channel stats.  meanp[b,l] = mean_c / sqrt(var_c (ddof=1))
// ---------------------------------------------------------------------------
__global__ __launch_bounds__(128) void stats_kernel(
    const float* __restrict__ dx, float* __restrict__ meanp)
{
    int id = blockIdx.x * 128 + threadIdx.x;   // 0 .. B*L-1 = 8191
    if (id >= BB * LL) return;
    int b = id >> 9;          // / 512
    int l = id & 511;
    const float* p = dx + (size_t)b * CC * LL + l;
    float s = 0.f, sq = 0.f;
#pragma unroll 8
    for (int c = 0; c < CC; ++c) {
        float v = p[(size_t)c * LL];
        s  += v;
        sq += v * v;
    }
    float mean = s * (1.0f / CC);
    float var  = (sq - (float)CC * mean * mean) * (1.0f / (CC - 1));
    meanp[id] = mean / sqrtf(var);
}

// ---------------------------------------------------------------------------
// Kernel B: one block per (b,c) series. Transform -> scan-based decompose ->
// features -> 48x1024 matvec -> write ONE 1024-float result row (no broadcast).
// ---------------------------------------------------------------------------
__global__ __launch_bounds__(256) void series_kernel(
    const float* __restrict__ dx,    const float* __restrict__ gamma,
    const float* __restrict__ beta,  const float* __restrict__ meanp,
    const float* __restrict__ w_t,   const float* __restrict__ b_t,
    const float* __restrict__ w_s,   const float* __restrict__ b_s,
    const float* __restrict__ w_r,   const float* __restrict__ b_r,
    const float* __restrict__ w_g,   const float* __restrict__ b_g,
    float* __restrict__ resbuf)
{
    __shared__ __align__(16) float xs[LL];        // transformed series
    __shared__ __align__(16) float pps[LL/2 + 1]; // pair-prefix sums (+lead 0)
    __shared__ __align__(16) float tvs[NV];       // trend (valid part)
    __shared__ __align__(16) float pas[PRD];      // demeaned period averages
    __shared__ __align__(16) float feats[48];     // [t(16) | s(16) | r(16)]
    __shared__ float wsum[4];                     // per-wave scan totals
    __shared__ float wred[4];                     // per-wave reduce partials

    const int tid  = threadIdx.x;              // 0..255
    const int lane = tid & 63;
    const int wv   = tid >> 6;
    const int bc   = blockIdx.x;               // 0..1023  (= b*64 + c)
    const int b    = bc >> 6;

    // ---- load + transform (float2 vectorized): x = gamma*(dx - meanp) + beta
    const size_t base = (size_t)bc * LL;
    float2 xv = ((const float2*)(dx    + base))[tid];
    float2 gv = ((const float2*)(gamma + base))[tid];
    float2 bv = ((const float2*)(beta  + base))[tid];
    float2 mv = ((const float2*)(meanp + (size_t)b * LL))[tid];
    float2 xp;
    xp.x = gv.x * (xv.x - mv.x) + bv.x;
    xp.y = gv.y * (xv.y - mv.y) + bv.y;
    ((float2*)xs)[tid] = xp;

    // ---- inclusive scan of pair-sums across the block (256 pairs)
    float v = xp.x + xp.y;
#pragma unroll
    for (int d = 1; d < 64; d <<= 1) {
        float t = __shfl_up(v, d, 64);
        if (lane >= d) v += t;
    }
    if (lane == 63) wsum[wv] = v;
    __syncthreads();
    float off = 0.f;
    for (int w = 0; w < wv; ++w) off += wsum[w];
    pps[tid + 1] = v + off;                    // pps[m+1] = sum of first 2(m+1) elems
    if (tid == 0) pps[0] = 0.f;
    __syncthreads();

    // ---- trend: W[i] = P(i+257) - P(i) - 0.5*(xs[i]+xs[i+256]);  tv = W/256
    // P(k) = pps[k>>1] + (k odd ? xs[k-1] : 0)
    const int i  = tid;
    const int k2 = i + 257;
    const float Pi = pps[i  >> 1] + ((i  & 1) ? xs[i  & ~1] : 0.f);
    const float Pk = pps[k2 >> 1] + ((k2 & 1) ? xs[k2 & ~1] : 0.f);
    const float x_i   = xs[i];
    const float x_i2  = xs[i + 256];
    const float tv = (Pk - Pi - 0.5f * (x_i + x_i2)) * (1.0f / 256.0f);
    tvs[i] = tv;
    const float dv = xs[HEAD + i] - tv;        // detrended valid sample

    // ---- mdv = mean(dv) over 256 samples
    float r = dv;
#pragma unroll
    for (int m = 32; m; m >>= 1) r += __shfl_xor(r, m, 64);
    if (lane == 0) wred[wv] = r;
    __syncthreads();
    const float mdv = (wred[0] + wred[1] + wred[2] + wred[3]) * (1.0f / 256.0f);

    // pa[(i+128)%256] = dv - mdv   (each phase occurs exactly once; nvalid == p)
    pas[(i + 128) & 255] = dv - mdv;
    __syncthreads();

    // ---- feature dot products (float4-chunked; 16 lanes cooperate per output)
    // resid is the constant mdv on [128,384): r[k] = mdv * sum(w_r[k,128:384]).
    {
        const int g  = tid >> 4;               // 0..15 : which output k
        const int ln = tid & 15;
        const float4* wt4  = (const float4*)(w_t + g * LL + HEAD);
        const float4* ws4a = (const float4*)(w_s + g * LL);
        const float4* ws4b = (const float4*)(w_s + g * LL + 256);
        const float4* wr4  = (const float4*)(w_r + g * LL + HEAD);
        const float4* tv4  = (const float4*)tvs;
        const float4* pa4  = (const float4*)pas;
        float at = 0.f, as = 0.f, ar = 0.f;
#pragma unroll
        for (int q = 0; q < 4; ++q) {
            const int m = ln * 4 + q;           // float4 index 0..63
            float4 t  = tv4[m],  p  = pa4[m];
            float4 a  = wt4[m];
            float4 s1 = ws4a[m], s2 = ws4b[m];
            float4 rr = wr4[m];
            at += t.x * a.x + t.y * a.y + t.z * a.z + t.w * a.w;
            as += p.x * (s1.x + s2.x) + p.y * (s1.y + s2.y)
                + p.z * (s1.z + s2.z) + p.w * (s1.w + s2.w);
            ar += rr.x + rr.y + rr.z + rr.w;
        }
#pragma unroll
        for (int msk = 8; msk; msk >>= 1) {
            at += __shfl_xor(at, msk, 64);
            as += __shfl_xor(as, msk, 64);
            ar += __shfl_xor(ar, msk, 64);
        }
        if (ln == 0) {
            feats[g]      = at + b_t[g];
            feats[16 + g] = as + b_s[g];
            feats[32 + g] = mdv * ar + b_r[g];
        }
    }
    __syncthreads();

    // ---- g[d] = feats . w_g[d,:] + b_g[d], 4 consecutive d per thread
    float fr[48];
#pragma unroll
    for (int j = 0; j < 48; ++j) fr[j] = feats[j];

    const int d0 = tid * 4;
    float a[4];
#pragma unroll
    for (int row = 0; row < 4; ++row) {
        const float4* w4 = (const float4*)(w_g + (size_t)(d0 + row) * 48);
        float acc = b_g[d0 + row];
#pragma unroll
        for (int q = 0; q < 12; ++q) {
            float4 w = w4[q];
            acc += w.x * fr[q * 4 + 0] + w.y * fr[q * 4 + 1]
                 + w.z * fr[q * 4 + 2] + w.w * fr[q * 4 + 3];
        }
        a[row] = acc;
    }
    f32x4 res;
    res.x = a[0]; res.y = a[1]; res.z = a[2]; res.w = a[3];

    ((f32x4*)resbuf)[(size_t)bc * (DM / 4) + tid] = res;
}

// ---------------------------------------------------------------------------
// Kernel C: pure broadcast store, shaped like fillBuffer. 16384 blocks x 256.
// Block k covers 16 KiB of out: bc = k>>4, patches 4*(k&15) .. +3.
// ---------------------------------------------------------------------------
__global__ __launch_bounds__(256) void bcast_kernel(
    const float* __restrict__ resbuf, float* __restrict__ out)
{
    const int k  = blockIdx.x;                 // 0..16383
    const int t  = threadIdx.x;                // 0..255
    const int bc = k >> 4;
    const int j  = k & 15;
    const f32x4 v = ((const f32x4*)resbuf)[(size_t)bc * (DM / 4) + t];
    f32x4* op = (f32x4*)out + (size_t)bc * (NP * DM / 4)
              + (size_t)j * (4 * DM / 4) + t;
#pragma unroll
    for (int n = 0; n < 4; ++n)
        __builtin_nontemporal_store(v, op + (size_t)n * (DM / 4));
}

// ---------------------------------------------------------------------------
extern "C" void kernel_launch(void* const* d_in, const int* in_sizes, int n_in,
                              void* d_out, int out_size, void* d_ws, size_t ws_size,
                              hipStream_t stream) {
    const float* dx    = (const float*)d_in[0];
    const float* gamma = (const float*)d_in[1];
    const float* beta  = (const float*)d_in[2];
    const float* w_t   = (const float*)d_in[3];
    const float* b_t   = (const float*)d_in[4];
    const float* w_s   = (const float*)d_in[5];
    const float* b_s   = (const float*)d_in[6];
    const float* w_r   = (const float*)d_in[7];
    const float* b_r   = (const float*)d_in[8];
    const float* w_g   = (const float*)d_in[9];
    const float* b_g   = (const float*)d_in[10];
    float* out = (float*)d_out;

    float* meanp  = (float*)d_ws;                    // B*L = 8192 floats
    float* resbuf = (float*)d_ws + 8192;             // 1024*1024 floats (4 MB)

    stats_kernel<<<(BB * LL + 127) / 128, 128, 0, stream>>>(dx, meanp);
    series_kernel<<<BB * CC, 256, 0, stream>>>(
        dx, gamma, beta, meanp,
        w_t, b_t, w_s, b_s, w_r, b_r, w_g, b_g, resbuf);
    bcast_kernel<<<BB * CC * 16, 256, 0, stream>>>(resbuf, out);
}

// Round 5
// 79.364 us; speedup vs baseline: 1.2985x; 1.2985x over previous
//
#include <hip/hip_runtime.h>
#include <math.h>

// Problem constants (match reference)
#define BB   16
#define CC   64
#define LL   512
#define LP   16
#define DM   1024
#define NP   64
#define PRD  256   // period = L/2
#define HEAD 128   // PRD/2
#define NV   256   // L - PRD

typedef float f32x4 __attribute__((ext_vector_type(4)));

// workspace layout (in floats); all offsets 16B-aligned
#define OFF_MEANP 0                    // 8192
#define OFF_WSF   8192                 // 16*256 folded seasonal weights
#define OFF_WRS   (8192 + 4096)        // 16 resid weight sums
#define OFF_FEATS 12304                // 1024*48
#define OFF_RES   (12304 + 49152)      // 1024*1024 result table

// ---------------------------------------------------------------------------
// Kernel 1: blocks 0..31 = per-(b,l) channel stats; block 32 = weight folding.
// ---------------------------------------------------------------------------
__global__ __launch_bounds__(256) void statsprep_kernel(
    const float* __restrict__ dx, const float* __restrict__ w_s,
    const float* __restrict__ w_r, float* __restrict__ ws)
{
    const int tid = threadIdx.x, bid = blockIdx.x;
    if (bid < 32) {
        int id = bid * 256 + tid;            // 0..8191
        int b = id >> 9, l = id & 511;
        const float* p = dx + (size_t)b * CC * LL + l;
        float s = 0.f, sq = 0.f;
#pragma unroll 8
        for (int c = 0; c < CC; ++c) {
            float v = p[(size_t)c * LL];
            s += v; sq += v * v;
        }
        float mean = s * (1.0f / CC);
        float var  = (sq - (float)CC * mean * mean) * (1.0f / (CC - 1));
        ws[OFF_MEANP + id] = mean / sqrtf(var);
    } else {
        // fold seasonal weights: wsf[g][m] = w_s[g][m] + w_s[g][m+256]
#pragma unroll
        for (int idx = tid; idx < 16 * PRD; idx += 256) {
            int g = idx >> 8, m = idx & 255;
            ws[OFF_WSF + idx] = w_s[g * LL + m] + w_s[g * LL + PRD + m];
        }
        // resid weight sums: wrs[g] = sum w_r[g][128:384]
        int g = tid >> 4, ln = tid & 15;
        float s = 0.f;
        for (int k = ln; k < PRD; k += 16) s += w_r[g * LL + HEAD + k];
#pragma unroll
        for (int m = 8; m; m >>= 1) s += __shfl_xor(s, m, 16);
        if (ln == 0) ws[OFF_WRS + g] = s;
    }
}

// ---------------------------------------------------------------------------
// Kernel 2: one block per (b,c). Transform -> scan decompose -> 48 features.
// ---------------------------------------------------------------------------
__global__ __launch_bounds__(256) void feats_kernel(
    const float* __restrict__ dx,    const float* __restrict__ gamma,
    const float* __restrict__ beta,  const float* __restrict__ w_t,
    const float* __restrict__ b_t,   const float* __restrict__ b_s,
    const float* __restrict__ b_r,   float* __restrict__ ws)
{
    __shared__ __align__(16) float xs[LL];
    __shared__ __align__(16) float pps[LL/2 + 1];
    __shared__ __align__(16) float tvs[NV];
    __shared__ __align__(16) float pas[PRD];
    __shared__ __align__(16) float feats[48];
    __shared__ float wsum[4];
    __shared__ float wred[4];

    const int tid  = threadIdx.x;
    const int lane = tid & 63;
    const int wv   = tid >> 6;
    const int bc   = blockIdx.x;
    const int b    = bc >> 6;

    // transform (float2): x = gamma*(dx - meanp) + beta
    const size_t base = (size_t)bc * LL;
    float2 xv = ((const float2*)(dx    + base))[tid];
    float2 gv = ((const float2*)(gamma + base))[tid];
    float2 bv = ((const float2*)(beta  + base))[tid];
    float2 mv = ((const float2*)(ws + OFF_MEANP + (size_t)b * LL))[tid];
    float2 xp;
    xp.x = gv.x * (xv.x - mv.x) + bv.x;
    xp.y = gv.y * (xv.y - mv.y) + bv.y;
    ((float2*)xs)[tid] = xp;

    // inclusive scan of pair-sums (256 pairs)
    float v = xp.x + xp.y;
#pragma unroll
    for (int d = 1; d < 64; d <<= 1) {
        float t = __shfl_up(v, d, 64);
        if (lane >= d) v += t;
    }
    if (lane == 63) wsum[wv] = v;
    __syncthreads();
    float off = 0.f;
    for (int w = 0; w < wv; ++w) off += wsum[w];
    pps[tid + 1] = v + off;
    if (tid == 0) pps[0] = 0.f;
    __syncthreads();

    // trend via prefix sums
    const int i  = tid;
    const int k2 = i + 257;
    const float Pi = pps[i  >> 1] + ((i  & 1) ? xs[i  & ~1] : 0.f);
    const float Pk = pps[k2 >> 1] + ((k2 & 1) ? xs[k2 & ~1] : 0.f);
    const float tv = (Pk - Pi - 0.5f * (xs[i] + xs[i + 256])) * (1.0f / 256.0f);
    tvs[i] = tv;
    const float dv = xs[HEAD + i] - tv;

    // mdv = mean(dv)
    float r = dv;
#pragma unroll
    for (int m = 32; m; m >>= 1) r += __shfl_xor(r, m, 64);
    if (lane == 0) wred[wv] = r;
    __syncthreads();
    const float mdv = (wred[0] + wred[1] + wred[2] + wred[3]) * (1.0f / 256.0f);

    pas[(i + 128) & 255] = dv - mdv;
    __syncthreads();

    // feature dots with folded weights (8 float4 loads/thread)
    {
        const int g  = tid >> 4;
        const int ln = tid & 15;
        const f32x4* wt4  = (const f32x4*)(w_t + g * LL + HEAD);
        const f32x4* wsf4 = (const f32x4*)(ws + OFF_WSF + g * PRD);
        const f32x4* tv4  = (const f32x4*)tvs;
        const f32x4* pa4  = (const f32x4*)pas;
        float at = 0.f, as = 0.f;
#pragma unroll
        for (int q = 0; q < 4; ++q) {
            const int m = ln * 4 + q;
            f32x4 t = tv4[m], p = pa4[m];
            f32x4 a = wt4[m], sfw = wsf4[m];
            at += t.x * a.x + t.y * a.y + t.z * a.z + t.w * a.w;
            as += p.x * sfw.x + p.y * sfw.y + p.z * sfw.z + p.w * sfw.w;
        }
#pragma unroll
        for (int msk = 8; msk; msk >>= 1) {
            at += __shfl_xor(at, msk, 64);
            as += __shfl_xor(as, msk, 64);
        }
        if (ln == 0) {
            feats[g]      = at + b_t[g];
            feats[16 + g] = as + b_s[g];
            feats[32 + g] = mdv * ws[OFF_WRS + g] + b_r[g];
        }
    }
    __syncthreads();

    // write 48-float feature row
    if (tid < 12)
        ((f32x4*)(ws + OFF_FEATS))[bc * 12 + tid] = ((const f32x4*)feats)[tid];
}

// ---------------------------------------------------------------------------
// Kernel 3: tiled matvec. Block = (bctile of 64) x (dtile of 64). 256 blocks.
// feats tile staged in LDS (wave-uniform broadcast reads); w_g row in regs.
// ---------------------------------------------------------------------------
__global__ __launch_bounds__(256) void gemm_kernel(
    const float* __restrict__ ws, const float* __restrict__ w_g,
    const float* __restrict__ b_g, float* __restrict__ resbuf)
{
    __shared__ f32x4 sfeat[64 * 12];        // 12 KB
    const int tid    = threadIdx.x;
    const int bctile = blockIdx.x >> 4;
    const int dtile  = blockIdx.x & 15;

    const f32x4* fsrc = (const f32x4*)(ws + OFF_FEATS) + bctile * 64 * 12;
#pragma unroll
    for (int q = 0; q < 3; ++q) sfeat[q * 256 + tid] = fsrc[q * 256 + tid];
    __syncthreads();

    const int dl  = tid & 63, wid = tid >> 6;
    const int d   = dtile * 64 + dl;
    f32x4 wrow[12];
    const f32x4* wg4 = (const f32x4*)(w_g + (size_t)d * 48);
#pragma unroll
    for (int j = 0; j < 12; ++j) wrow[j] = wg4[j];
    const float bg = b_g[d];

    float* rb = resbuf + (size_t)(bctile * 64 + wid * 16) * DM + d;
#pragma unroll
    for (int r = 0; r < 16; ++r) {
        const f32x4* fr = &sfeat[(wid * 16 + r) * 12];
        float acc = bg;
#pragma unroll
        for (int j = 0; j < 12; ++j) {
            f32x4 f = fr[j], w = wrow[j];
            acc += f.x * w.x + f.y * w.y + f.z * w.z + f.w * w.w;
        }
        rb[(size_t)r * DM] = acc;
    }
}

// ---------------------------------------------------------------------------
// Kernel 4: broadcast store. 4096 blocks; block = (bc, quarter of patches).
// 16 independent nt f32x4 stores per thread, 64 KB per block.
// ---------------------------------------------------------------------------
__global__ __launch_bounds__(256) void bcast_kernel(
    const float* __restrict__ resbuf, float* __restrict__ out)
{
    const int tid = threadIdx.x;
    const int bc  = blockIdx.x >> 2;
    const int q   = blockIdx.x & 3;
    const f32x4 v = ((const f32x4*)resbuf)[bc * (DM / 4) + tid];
    f32x4* op = (f32x4*)out + (size_t)bc * (NP * DM / 4)
              + (size_t)q * 16 * (DM / 4) + tid;
#pragma unroll
    for (int n = 0; n < 16; ++n)
        __builtin_nontemporal_store(v, op + (size_t)n * (DM / 4));
}

// ---------------------------------------------------------------------------
extern "C" void kernel_launch(void* const* d_in, const int* in_sizes, int n_in,
                              void* d_out, int out_size, void* d_ws, size_t ws_size,
                              hipStream_t stream) {
    const float* dx    = (const float*)d_in[0];
    const float* gamma = (const float*)d_in[1];
    const float* beta  = (const float*)d_in[2];
    const float* w_t   = (const float*)d_in[3];
    const float* b_t   = (const float*)d_in[4];
    const float* w_s   = (const float*)d_in[5];
    const float* b_s   = (const float*)d_in[6];
    const float* w_r   = (const float*)d_in[7];
    const float* b_r   = (const float*)d_in[8];
    const float* w_g   = (const float*)d_in[9];
    const float* b_g   = (const float*)d_in[10];
    float* out = (float*)d_out;
    float* ws  = (float*)d_ws;
    float* resbuf = ws + OFF_RES;

    statsprep_kernel<<<33, 256, 0, stream>>>(dx, w_s, w_r, ws);
    feats_kernel<<<BB * CC, 256, 0, stream>>>(
        dx, gamma, beta, w_t, b_t, b_s, b_r, ws);
    gemm_kernel<<<256, 256, 0, stream>>>(ws, w_g, b_g, resbuf);
    bcast_kernel<<<BB * CC * 4, 256, 0, stream>>>(resbuf, out);
}

// Round 6
// 74.931 us; speedup vs baseline: 1.3753x; 1.0592x over previous
//
#include <hip/hip_runtime.h>
#include <math.h>

// Problem constants (match reference)
#define BB   16
#define CC   64
#define LL   512
#define LP   16
#define DM   1024
#define NP   64
#define PRD  256   // period = L/2
#define HEAD 128   // PRD/2
#define NV   256   // L - PRD

typedef float f32x4 __attribute__((ext_vector_type(4)));

// workspace layout (in floats); all offsets 16B-aligned
#define OFF_MEANP 0                    // 8192
#define OFF_WSF   8192                 // 16*256 folded seasonal weights
#define OFF_WRS   (8192 + 4096)        // 16 resid weight sums
#define OFF_FEATS 12304                // 1024*48
#define OFF_RES   (12304 + 49152)      // 1024*1024 result table

// ---------------------------------------------------------------------------
// Kernel 1: blocks 0..31 = per-(b,l) channel stats; block 32 = weight folding.
// ---------------------------------------------------------------------------
__global__ __launch_bounds__(256) void statsprep_kernel(
    const float* __restrict__ dx, const float* __restrict__ w_s,
    const float* __restrict__ w_r, float* __restrict__ ws)
{
    const int tid = threadIdx.x, bid = blockIdx.x;
    if (bid < 32) {
        int id = bid * 256 + tid;            // 0..8191
        int b = id >> 9, l = id & 511;
        const float* p = dx + (size_t)b * CC * LL + l;
        float s = 0.f, sq = 0.f;
#pragma unroll 8
        for (int c = 0; c < CC; ++c) {
            float v = p[(size_t)c * LL];
            s += v; sq += v * v;
        }
        float mean = s * (1.0f / CC);
        float var  = (sq - (float)CC * mean * mean) * (1.0f / (CC - 1));
        ws[OFF_MEANP + id] = mean / sqrtf(var);
    } else {
        // fold seasonal weights: wsf[g][m] = w_s[g][m] + w_s[g][m+256]
#pragma unroll
        for (int idx = tid; idx < 16 * PRD; idx += 256) {
            int g = idx >> 8, m = idx & 255;
            ws[OFF_WSF + idx] = w_s[g * LL + m] + w_s[g * LL + PRD + m];
        }
        // resid weight sums: wrs[g] = sum w_r[g][128:384]
        int g = tid >> 4, ln = tid & 15;
        float s = 0.f;
        for (int k = ln; k < PRD; k += 16) s += w_r[g * LL + HEAD + k];
#pragma unroll
        for (int m = 8; m; m >>= 1) s += __shfl_xor(s, m, 16);
        if (ln == 0) ws[OFF_WRS + g] = s;
    }
}

// ---------------------------------------------------------------------------
// Kernel 2: one block per (b,c). Transform -> scan decompose -> 48 features.
// ---------------------------------------------------------------------------
__global__ __launch_bounds__(256) void feats_kernel(
    const float* __restrict__ dx,    const float* __restrict__ gamma,
    const float* __restrict__ beta,  const float* __restrict__ w_t,
    const float* __restrict__ b_t,   const float* __restrict__ b_s,
    const float* __restrict__ b_r,   float* __restrict__ ws)
{
    __shared__ __align__(16) float xs[LL];
    __shared__ __align__(16) float pps[LL/2 + 1];
    __shared__ __align__(16) float tvs[NV];
    __shared__ __align__(16) float pas[PRD];
    __shared__ __align__(16) float feats[48];
    __shared__ float wsum[4];
    __shared__ float wred[4];

    const int tid  = threadIdx.x;
    const int lane = tid & 63;
    const int wv   = tid >> 6;
    const int bc   = blockIdx.x;
    const int b    = bc >> 6;

    // transform (float2): x = gamma*(dx - meanp) + beta
    const size_t base = (size_t)bc * LL;
    float2 xv = ((const float2*)(dx    + base))[tid];
    float2 gv = ((const float2*)(gamma + base))[tid];
    float2 bv = ((const float2*)(beta  + base))[tid];
    float2 mv = ((const float2*)(ws + OFF_MEANP + (size_t)b * LL))[tid];
    float2 xp;
    xp.x = gv.x * (xv.x - mv.x) + bv.x;
    xp.y = gv.y * (xv.y - mv.y) + bv.y;
    ((float2*)xs)[tid] = xp;

    // inclusive scan of pair-sums (256 pairs)
    float v = xp.x + xp.y;
#pragma unroll
    for (int d = 1; d < 64; d <<= 1) {
        float t = __shfl_up(v, d, 64);
        if (lane >= d) v += t;
    }
    if (lane == 63) wsum[wv] = v;
    __syncthreads();
    float off = 0.f;
    for (int w = 0; w < wv; ++w) off += wsum[w];
    pps[tid + 1] = v + off;
    if (tid == 0) pps[0] = 0.f;
    __syncthreads();

    // trend via prefix sums
    const int i  = tid;
    const int k2 = i + 257;
    const float Pi = pps[i  >> 1] + ((i  & 1) ? xs[i  & ~1] : 0.f);
    const float Pk = pps[k2 >> 1] + ((k2 & 1) ? xs[k2 & ~1] : 0.f);
    const float tv = (Pk - Pi - 0.5f * (xs[i] + xs[i + 256])) * (1.0f / 256.0f);
    tvs[i] = tv;
    const float dv = xs[HEAD + i] - tv;

    // mdv = mean(dv)
    float r = dv;
#pragma unroll
    for (int m = 32; m; m >>= 1) r += __shfl_xor(r, m, 64);
    if (lane == 0) wred[wv] = r;
    __syncthreads();
    const float mdv = (wred[0] + wred[1] + wred[2] + wred[3]) * (1.0f / 256.0f);

    pas[(i + 128) & 255] = dv - mdv;
    __syncthreads();

    // feature dots with folded weights (8 float4 loads/thread)
    {
        const int g  = tid >> 4;
        const int ln = tid & 15;
        const f32x4* wt4  = (const f32x4*)(w_t + g * LL + HEAD);
        const f32x4* wsf4 = (const f32x4*)(ws + OFF_WSF + g * PRD);
        const f32x4* tv4  = (const f32x4*)tvs;
        const f32x4* pa4  = (const f32x4*)pas;
        float at = 0.f, as = 0.f;
#pragma unroll
        for (int q = 0; q < 4; ++q) {
            const int m = ln * 4 + q;
            f32x4 t = tv4[m], p = pa4[m];
            f32x4 a = wt4[m], sfw = wsf4[m];
            at += t.x * a.x + t.y * a.y + t.z * a.z + t.w * a.w;
            as += p.x * sfw.x + p.y * sfw.y + p.z * sfw.z + p.w * sfw.w;
        }
#pragma unroll
        for (int msk = 8; msk; msk >>= 1) {
            at += __shfl_xor(at, msk, 64);
            as += __shfl_xor(as, msk, 64);
        }
        if (ln == 0) {
            feats[g]      = at + b_t[g];
            feats[16 + g] = as + b_s[g];
            feats[32 + g] = mdv * ws[OFF_WRS + g] + b_r[g];
        }
    }
    __syncthreads();

    // write 48-float feature row
    if (tid < 12)
        ((f32x4*)(ws + OFF_FEATS))[bc * 12 + tid] = ((const f32x4*)feats)[tid];
}

// ---------------------------------------------------------------------------
// Kernel 3: tiled matvec. Block = (bctile of 64) x (dtile of 64). 256 blocks.
// feats tile staged in LDS (wave-uniform broadcast reads); w_g row in regs.
// ---------------------------------------------------------------------------
__global__ __launch_bounds__(256) void gemm_kernel(
    const float* __restrict__ ws, const float* __restrict__ w_g,
    const float* __restrict__ b_g, float* __restrict__ resbuf)
{
    __shared__ f32x4 sfeat[64 * 12];        // 12 KB
    const int tid    = threadIdx.x;
    const int bctile = blockIdx.x >> 4;
    const int dtile  = blockIdx.x & 15;

    const f32x4* fsrc = (const f32x4*)(ws + OFF_FEATS) + bctile * 64 * 12;
#pragma unroll
    for (int q = 0; q < 3; ++q) sfeat[q * 256 + tid] = fsrc[q * 256 + tid];
    __syncthreads();

    const int dl  = tid & 63, wid = tid >> 6;
    const int d   = dtile * 64 + dl;
    f32x4 wrow[12];
    const f32x4* wg4 = (const f32x4*)(w_g + (size_t)d * 48);
#pragma unroll
    for (int j = 0; j < 12; ++j) wrow[j] = wg4[j];
    const float bg = b_g[d];

    float* rb = resbuf + (size_t)(bctile * 64 + wid * 16) * DM + d;
#pragma unroll
    for (int r = 0; r < 16; ++r) {
        const f32x4* fr = &sfeat[(wid * 16 + r) * 12];
        float acc = bg;
#pragma unroll
        for (int j = 0; j < 12; ++j) {
            f32x4 f = fr[j], w = wrow[j];
            acc += f.x * w.x + f.y * w.y + f.z * w.z + f.w * w.w;
        }
        rb[(size_t)r * DM] = acc;
    }
}

// ---------------------------------------------------------------------------
// Kernel 4: broadcast store. 4096 blocks; block = (bc, quarter of patches).
// 16 independent PLAIN f32x4 stores per thread, 64 KB per block.
// (A/B vs R5: nt stores removed — testing whether nt bypass throttles writes)
// ---------------------------------------------------------------------------
__global__ __launch_bounds__(256) void bcast_kernel(
    const float* __restrict__ resbuf, float* __restrict__ out)
{
    const int tid = threadIdx.x;
    const int bc  = blockIdx.x >> 2;
    const int q   = blockIdx.x & 3;
    const f32x4 v = ((const f32x4*)resbuf)[bc * (DM / 4) + tid];
    f32x4* op = (f32x4*)out + (size_t)bc * (NP * DM / 4)
              + (size_t)q * 16 * (DM / 4) + tid;
#pragma unroll
    for (int n = 0; n < 16; ++n)
        op[(size_t)n * (DM / 4)] = v;
}

// ---------------------------------------------------------------------------
extern "C" void kernel_launch(void* const* d_in, const int* in_sizes, int n_in,
                              void* d_out, int out_size, void* d_ws, size_t ws_size,
                              hipStream_t stream) {
    const float* dx    = (const float*)d_in[0];
    const float* gamma = (const float*)d_in[1];
    const float* beta  = (const float*)d_in[2];
    const float* w_t   = (const float*)d_in[3];
    const float* b_t   = (const float*)d_in[4];
    const float* w_s   = (const float*)d_in[5];
    const float* b_s   = (const float*)d_in[6];
    const float* w_r   = (const float*)d_in[7];
    const float* b_r   = (const float*)d_in[8];
    const float* w_g   = (const float*)d_in[9];
    const float* b_g   = (const float*)d_in[10];
    float* out = (float*)d_out;
    float* ws  = (float*)d_ws;
    float* resbuf = ws + OFF_RES;

    statsprep_kernel<<<33, 256, 0, stream>>>(dx, w_s, w_r, ws);
    feats_kernel<<<BB * CC, 256, 0, stream>>>(
        dx, gamma, beta, w_t, b_t, b_s, b_r, ws);
    gemm_kernel<<<256, 256, 0, stream>>>(ws, w_g, b_g, resbuf);
    bcast_kernel<<<BB * CC * 4, 256, 0, stream>>>(resbuf, out);
}